// Round 2
// baseline (1006.414 us; speedup 1.0000x reference)
//
#include <hip/hip_runtime.h>

#define NN 100000
#define NE 6400000
#define NEG_SLOPE 0.2f

// ---------------- zero the replica accumulators ----------------
__global__ void gat_zero(float4* __restrict__ acc, int n4) {
    int i = blockIdx.x * blockDim.x + threadIdx.x;
    int st = gridDim.x * blockDim.x;
    float4 z = make_float4(0.f, 0.f, 0.f, 0.f);
    for (; i < n4; i += st) acc[i] = z;
}

// ---------------- node pass: pack = {h0, h1, a_src, a_dst} ----------------
// One 64-lane wave per node row; lane l covers features 2l, 2l+1.
__global__ void gat_node(const float* __restrict__ x, const float* __restrict__ W,
                         const float* __restrict__ att_src, const float* __restrict__ att_dst,
                         float4* __restrict__ pack, int n) {
    int gtid = blockIdx.x * blockDim.x + threadIdx.x;
    int wave = gtid >> 6, lane = threadIdx.x & 63;
    int nw = (gridDim.x * blockDim.x) >> 6;
    float as0 = att_src[0], as1 = att_src[1];
    float ad0 = att_dst[0], ad1 = att_dst[1];
    for (int node = wave; node < n; node += nw) {
        float2 xx = *(const float2*)(x + (size_t)node * 128 + lane * 2);
        float2 w0 = *(const float2*)(W + lane * 4);
        float2 w1 = *(const float2*)(W + lane * 4 + 2);
        float c0 = xx.x * w0.x + xx.y * w1.x;
        float c1 = xx.x * w0.y + xx.y * w1.y;
        #pragma unroll
        for (int off = 32; off; off >>= 1) {
            c0 += __shfl_down(c0, off);
            c1 += __shfl_down(c1, off);
        }
        if (lane == 0)
            pack[node] = make_float4(c0, c1, c0 * as0 + c1 * as1, c0 * ad0 + c1 * ad1);
    }
}

// ---------------- fused edge pass: ex + 3 accumulations ----------------
// LOCAL=true: replica = this block's physical XCD (s_getreg XCC_ID), atomics at
// workgroup scope -> executed in the XCD's own L2 (write-back, cached), never
// routed to the memory-side coherence point. Only blocks on XCD r touch
// replica r, so L2-local atomicity is sufficient.
template<bool LOCAL>
__global__ void gat_edge(const int* __restrict__ src, const int* __restrict__ dst,
                         const float* __restrict__ ea, const float4* __restrict__ pack,
                         const float* __restrict__ W_edge, const float* __restrict__ att_edge,
                         float* __restrict__ exbuf, float* __restrict__ acc,
                         int repmask, int ne) {
    int rep;
    if (LOCAL) {
        unsigned xcc;
        asm volatile("s_getreg_b32 %0, hwreg(HW_REG_XCC_ID)" : "=s"(xcc));
        rep = (int)(xcc & 7u);
    } else {
        rep = blockIdx.x & repmask;
    }
    float* accr = acc + (size_t)rep * NN * 4;
    float k = W_edge[0] * att_edge[0] + W_edge[1] * att_edge[1];
    const float* packf = (const float*)pack;
    int i = blockIdx.x * blockDim.x + threadIdx.x;
    int st = gridDim.x * blockDim.x;
    for (; i < ne; i += st) {
        int s = src[i], d = dst[i];
        float4 ps = pack[s];                       // h0, h1, a_src, -
        float adv = packf[4 * (size_t)d + 3];      // a_dst[d]
        float al = ps.z + adv + k * ea[i];
        al = al > 0.f ? al : NEG_SLOPE * al;
        float ex = __expf(al);
        exbuf[i] = ex;
        float* p = accr + 4 * (size_t)d;           // {denom, num0, num1, pad}
        if (LOCAL) {
            __hip_atomic_fetch_add(p,     ex,          __ATOMIC_RELAXED, __HIP_MEMORY_SCOPE_WORKGROUP);
            __hip_atomic_fetch_add(p + 1, ex * ps.x,   __ATOMIC_RELAXED, __HIP_MEMORY_SCOPE_WORKGROUP);
            __hip_atomic_fetch_add(p + 2, ex * ps.y,   __ATOMIC_RELAXED, __HIP_MEMORY_SCOPE_WORKGROUP);
        } else {
            atomicAdd(p,     ex);
            atomicAdd(p + 1, ex * ps.x);
            atomicAdd(p + 2, ex * ps.y);
        }
    }
}

// ---------------- combine replicas: out = num/denom + bias, invd = 1/denom --
__global__ void gat_combine(const float4* __restrict__ acc, int nrep,
                            const float* __restrict__ bias,
                            float* __restrict__ out, float* __restrict__ invd, int n) {
    int i = blockIdx.x * blockDim.x + threadIdx.x;
    int st = gridDim.x * blockDim.x;
    float b0 = bias[0], b1 = bias[1];
    for (; i < n; i += st) {
        float de = 0.f, n0 = 0.f, n1 = 0.f;
        for (int r = 0; r < nrep; ++r) {
            float4 a = acc[(size_t)r * NN + i];
            de += a.x; n0 += a.y; n1 += a.z;
        }
        float inv = 1.0f / (de + 1e-16f);
        out[2 * i]     = n0 * inv + b0;
        out[2 * i + 1] = n1 * inv + b1;
        invd[i] = inv;
    }
}

// ---------------- finalize alpha: alpha[i] = ex[i] * invd[dst[i]] ----------
__global__ void gat_alpha(const int* __restrict__ dst, const float* __restrict__ invd,
                          float* __restrict__ alpha, int ne) {
    int i = blockIdx.x * blockDim.x + threadIdx.x;
    int st = gridDim.x * blockDim.x;
    for (; i < ne; i += st) alpha[i] *= invd[dst[i]];
}

extern "C" void kernel_launch(void* const* d_in, const int* in_sizes, int n_in,
                              void* d_out, int out_size, void* d_ws, size_t ws_size,
                              hipStream_t stream) {
    const float* x        = (const float*)d_in[0];
    const int*   ei       = (const int*)  d_in[1];
    const float* ea       = (const float*)d_in[2];
    const float* W_src    = (const float*)d_in[3];
    const float* W_edge   = (const float*)d_in[4];
    const float* att_src  = (const float*)d_in[5];
    const float* att_dst  = (const float*)d_in[6];
    const float* att_edge = (const float*)d_in[7];
    const float* bias     = (const float*)d_in[8];

    float* out   = (float*)d_out;        // [N,2] flat
    float* alpha = out + 2 * NN;         // [E] flat: ex stash, then alpha

    // pick replica count from ws budget: acc[R][N] float4 | pack[N] float4 | invd[N]
    auto need = [](int r) { return (size_t)(r + 1) * NN * 16 + (size_t)NN * 4; };
    int R = 8;
    while (R > 1 && need(R) > ws_size) R >>= 1;
    bool local = (R == 8);

    float4* acc  = (float4*)d_ws;
    float4* pack = acc + (size_t)R * NN;
    float*  invd = (float*)(pack + NN);

    const int* src = ei;            // edge_index[0]
    const int* dst = ei + NE;       // edge_index[1]

    gat_zero<<<1024, 256, 0, stream>>>(acc, R * NN);
    gat_node<<<1024, 256, 0, stream>>>(x, W_src, att_src, att_dst, pack, NN);
    if (local)
        gat_edge<true><<<4096, 256, 0, stream>>>(src, dst, ea, pack, W_edge, att_edge,
                                                 alpha, (float*)acc, R - 1, NE);
    else
        gat_edge<false><<<4096, 256, 0, stream>>>(src, dst, ea, pack, W_edge, att_edge,
                                                  alpha, (float*)acc, R - 1, NE);
    gat_combine<<<512, 256, 0, stream>>>(acc, R, bias, out, invd, NN);
    gat_alpha<<<2048, 256, 0, stream>>>(dst, invd, alpha, NE);
}

// Round 3
// 265.229 us; speedup vs baseline: 3.7945x; 3.7945x over previous
//
#include <hip/hip_runtime.h>

#define NN 100000
#define NE 6400000
#define NEG_SLOPE 0.2f

#define SLICE 10240           // nodes per LDS slice
#define NSLICE 10             // ceil(NN / SLICE)
#define NCHUNK 20             // edge chunks (blocks per slice)
#define CHUNK (NE / NCHUNK)   // 320000 edges, divisible by 4

// ---------------- node pass: pack = {h0, h1, a_src, a_dst} ----------------
__global__ void gat_node(const float* __restrict__ x, const float* __restrict__ W,
                         const float* __restrict__ att_src, const float* __restrict__ att_dst,
                         float4* __restrict__ pack, int n) {
    int gtid = blockIdx.x * blockDim.x + threadIdx.x;
    int wave = gtid >> 6, lane = threadIdx.x & 63;
    int nw = (gridDim.x * blockDim.x) >> 6;
    float as0 = att_src[0], as1 = att_src[1];
    float ad0 = att_dst[0], ad1 = att_dst[1];
    for (int node = wave; node < n; node += nw) {
        float2 xx = *(const float2*)(x + (size_t)node * 128 + lane * 2);
        float2 w0 = *(const float2*)(W + lane * 4);
        float2 w1 = *(const float2*)(W + lane * 4 + 2);
        float c0 = xx.x * w0.x + xx.y * w1.x;
        float c1 = xx.x * w0.y + xx.y * w1.y;
        #pragma unroll
        for (int off = 32; off; off >>= 1) {
            c0 += __shfl_down(c0, off);
            c1 += __shfl_down(c1, off);
        }
        if (lane == 0)
            pack[node] = make_float4(c0, c1, c0 * as0 + c1 * as1, c0 * ad0 + c1 * ad1);
    }
}

// ---------------- slice scan: LDS-owned accumulation, no global atomics ----
// block = (slice s, chunk c). Scans chunk c's edges; accepts dst in slice s;
// accumulates {denom, num0, num1} in LDS; dumps partial slab coalesced.
__global__ __launch_bounds__(1024) void
gat_scan(const int* __restrict__ src, const int* __restrict__ dst,
         const float* __restrict__ ea, const float4* __restrict__ pack,
         const float* __restrict__ W_edge, const float* __restrict__ att_edge,
         float* __restrict__ partial) {
    __shared__ float sacc[SLICE * 3];          // 122880 B LDS
    const int s = blockIdx.x / NCHUNK;
    const int c = blockIdx.x % NCHUNK;
    const int lo = s * SLICE;

    for (int j = threadIdx.x; j < SLICE * 3; j += 1024) sacc[j] = 0.0f;
    __syncthreads();

    const float k = W_edge[0] * att_edge[0] + W_edge[1] * att_edge[1];
    const float* packf = (const float*)pack;
    const int base = c * CHUNK;

    for (int o = threadIdx.x * 4; o < CHUNK; o += 1024 * 4) {
        const int i = base + o;
        int4   d4 = *(const int4*)(dst + i);
        int4   s4 = *(const int4*)(src + i);
        float4 e4 = *(const float4*)(ea + i);
        const int*   dp = (const int*)&d4;
        const int*   sp = (const int*)&s4;
        const float* ep = (const float*)&e4;
        #pragma unroll
        for (int u = 0; u < 4; ++u) {
            int d = dp[u];
            unsigned off = (unsigned)(d - lo);
            if (off < SLICE) {
                float4 ps = pack[sp[u]];                       // h0,h1,a_src,-
                float al = ps.z + packf[4 * (size_t)d + 3] + k * ep[u];
                al = al > 0.0f ? al : NEG_SLOPE * al;
                float ex = __expf(al);
                atomicAdd(&sacc[off * 3],     ex);             // ds_add_f32
                atomicAdd(&sacc[off * 3 + 1], ex * ps.x);
                atomicAdd(&sacc[off * 3 + 2], ex * ps.y);
            }
        }
    }
    __syncthreads();

    float* pout = partial + (size_t)(s * NCHUNK + c) * (SLICE * 3);
    for (int j = threadIdx.x; j < SLICE * 3; j += 1024) pout[j] = sacc[j];
}

// ---------------- combine partials: out = num/denom + bias, invd ----------
__global__ void gat_combine(const float* __restrict__ partial,
                            const float* __restrict__ bias,
                            float* __restrict__ out, float* __restrict__ invd) {
    int n = blockIdx.x * blockDim.x + threadIdx.x;
    if (n >= NN) return;
    int s = n / SLICE, off = n % SLICE;
    const float* pbase = partial + (size_t)s * NCHUNK * SLICE * 3 + (size_t)off * 3;
    float de = 0.f, n0 = 0.f, n1 = 0.f;
    for (int c = 0; c < NCHUNK; ++c) {
        const float* p = pbase + (size_t)c * SLICE * 3;
        de += p[0]; n0 += p[1]; n1 += p[2];
    }
    float inv = 1.0f / (de + 1e-16f);
    out[2 * n]     = n0 * inv + bias[0];
    out[2 * n + 1] = n1 * inv + bias[1];
    invd[n] = inv;
}

// ---------------- alpha pass: recompute ex, alpha = ex * invd[dst] --------
__global__ void gat_alpha(const int* __restrict__ src, const int* __restrict__ dst,
                          const float* __restrict__ ea, const float4* __restrict__ pack,
                          const float* __restrict__ W_edge, const float* __restrict__ att_edge,
                          const float* __restrict__ invd, float* __restrict__ alpha) {
    const float k = W_edge[0] * att_edge[0] + W_edge[1] * att_edge[1];
    const float* packf = (const float*)pack;
    int t = blockIdx.x * blockDim.x + threadIdx.x;
    int stride = gridDim.x * blockDim.x * 4;
    for (int i = t * 4; i < NE; i += stride) {
        int4   d4 = *(const int4*)(dst + i);
        int4   s4 = *(const int4*)(src + i);
        float4 e4 = *(const float4*)(ea + i);
        const int*   dp = (const int*)&d4;
        const int*   sp = (const int*)&s4;
        const float* ep = (const float*)&e4;
        float4 a;
        float* ap = (float*)&a;
        #pragma unroll
        for (int u = 0; u < 4; ++u) {
            int d = dp[u];
            float al = packf[4 * (size_t)sp[u] + 2] + packf[4 * (size_t)d + 3] + k * ep[u];
            al = al > 0.0f ? al : NEG_SLOPE * al;
            ap[u] = __expf(al) * invd[d];
        }
        *(float4*)(alpha + i) = a;
    }
}

extern "C" void kernel_launch(void* const* d_in, const int* in_sizes, int n_in,
                              void* d_out, int out_size, void* d_ws, size_t ws_size,
                              hipStream_t stream) {
    const float* x        = (const float*)d_in[0];
    const int*   ei       = (const int*)  d_in[1];
    const float* ea       = (const float*)d_in[2];
    const float* W_src    = (const float*)d_in[3];
    const float* W_edge   = (const float*)d_in[4];
    const float* att_src  = (const float*)d_in[5];
    const float* att_dst  = (const float*)d_in[6];
    const float* att_edge = (const float*)d_in[7];
    const float* bias     = (const float*)d_in[8];

    float* out   = (float*)d_out;      // [N,2]
    float* alpha = out + 2 * NN;       // [E] — used as partial-slab scratch first

    float4* pack = (float4*)d_ws;              // [N] {h0,h1,a_src,a_dst}
    float*  invd = (float*)(pack + NN);        // [N]

    const int* src = ei;
    const int* dst = ei + NE;

    // partial slabs live in the alpha region: 10*20*10240*3 = 6.144M floats <= 6.4M
    float* partial = alpha;

    gat_node   <<<1024, 256, 0, stream>>>(x, W_src, att_src, att_dst, pack, NN);
    gat_scan   <<<NSLICE * NCHUNK, 1024, 0, stream>>>(src, dst, ea, pack, W_edge, att_edge, partial);
    gat_combine<<<(NN + 255) / 256, 256, 0, stream>>>(partial, bias, out, invd);
    gat_alpha  <<<2048, 256, 0, stream>>>(src, dst, ea, pack, W_edge, att_edge, invd, alpha);
}